// Round 1
// baseline (504.399 us; speedup 1.0000x reference)
//
#include <hip/hip_runtime.h>
#include <math.h>

// GraphAttention: q,v [G=2048, N=256, D=128] f32; mask [G, N] i32; W [256] f32; b [1] f32
// out [G, D] f32.  Online-softmax single pass: q and v each read exactly once.

constexpr int NR  = 256;   // rows per group
constexpr int DIM = 128;   // d_q = d_v
constexpr float LALPHA  = 0.2f;
constexpr float NEG_INF = -9.0e15f;

__global__ __launch_bounds__(256) void graph_attn_kernel(
    const float* __restrict__ q,    // [G, NR, DIM]
    const float* __restrict__ v,    // [G, NR, DIM]
    const int*   __restrict__ mask, // [G, NR]
    const float* __restrict__ W,    // [2*DIM]
    const float* __restrict__ bptr, // [1]
    float*       __restrict__ out)  // [G, DIM]
{
    const int g    = blockIdx.x;
    const int t    = threadIdx.x;
    const int hw   = t >> 5;    // half-wave id 0..7, each owns rows hw, hw+8, ...
    const int lane = t & 31;    // lane within half-wave; owns cols 4*lane..4*lane+3

    __shared__ float s_mask[NR];        // 1.0 = keep, 0.0 = masked
    __shared__ float s_m[8], s_l[8];
    __shared__ float s_o[8][DIM];

    // Prefetch mask for this group (coalesced, 1 KB)
    s_mask[t] = (mask[g * NR + t] > 0) ? 1.0f : 0.0f;
    __syncthreads();

    // Per-lane slice of the weight vector (loop-invariant)
    const float4 wq = *(const float4*)(W + lane * 4);
    const float4 wv = *(const float4*)(W + DIM + lane * 4);
    const float bias = bptr[0];

    const float* qg = q + (size_t)g * NR * DIM;
    const float* vg = v + (size_t)g * NR * DIM;

    // Online softmax state (per half-wave; o is distributed: 4 floats/lane)
    float m = -INFINITY;
    float l = 0.0f;
    float4 o = make_float4(0.f, 0.f, 0.f, 0.f);

#pragma unroll 4
    for (int k = 0; k < NR / 8; ++k) {
        const int n = hw + (k << 3);
        const float4 q4 = *(const float4*)(qg + n * DIM + lane * 4);
        const float4 v4 = *(const float4*)(vg + n * DIM + lane * 4);

        // partial dot: q.Wq + v.Wv over this lane's 4+4 columns
        float e = q4.x * wq.x + q4.y * wq.y + q4.z * wq.z + q4.w * wq.w
                + v4.x * wv.x + v4.y * wv.y + v4.z * wv.z + v4.w * wv.w;
        // butterfly sum across the 32 lanes of this half-wave (xor<32 stays in-half)
        e += __shfl_xor(e, 1);
        e += __shfl_xor(e, 2);
        e += __shfl_xor(e, 4);
        e += __shfl_xor(e, 8);
        e += __shfl_xor(e, 16);
        e += bias;
        e = fmaxf(e, LALPHA * e);                 // leaky_relu (exact for all signs)
        e = (s_mask[n] > 0.f) ? e : NEG_INF;      // mask fill

        // online-softmax update
        const float m_new = fmaxf(m, e);
        const float scale = __expf(m - m_new);    // exp(-inf)=0 handles first iter
        const float p     = __expf(e - m_new);    // all-masked: exp(0)=1 -> uniform (matches ref)
        l = l * scale + p;
        o.x = o.x * scale + p * v4.x;
        o.y = o.y * scale + p * v4.y;
        o.z = o.z * scale + p * v4.z;
        o.w = o.w * scale + p * v4.w;
        m = m_new;
    }

    // Publish per-half-wave state
    if (lane == 0) { s_m[hw] = m; s_l[hw] = l; }
    *(float4*)(&s_o[hw][lane * 4]) = o;
    __syncthreads();

    // Merge 8 states; threads 0..127 each own one output dim
    if (t < DIM) {
        float M = s_m[0];
#pragma unroll
        for (int i = 1; i < 8; ++i) M = fmaxf(M, s_m[i]);
        float L = 0.f, O = 0.f;
#pragma unroll
        for (int i = 0; i < 8; ++i) {
            const float w = __expf(s_m[i] - M);   // all-masked half-waves get w=0 (or all w=1 if fully masked group)
            L += w * s_l[i];
            O += w * s_o[i][t];
        }
        out[(size_t)g * DIM + t] = O / L;
    }
}

extern "C" void kernel_launch(void* const* d_in, const int* in_sizes, int n_in,
                              void* d_out, int out_size, void* d_ws, size_t ws_size,
                              hipStream_t stream) {
    const float* q    = (const float*)d_in[0];
    const float* v    = (const float*)d_in[1];
    const int*   mask = (const int*)d_in[2];
    const float* W    = (const float*)d_in[3];
    const float* b    = (const float*)d_in[4];
    float* out = (float*)d_out;

    const int G = in_sizes[0] / (NR * DIM);   // 2048
    graph_attn_kernel<<<G, 256, 0, stream>>>(q, v, mask, W, b, out);
}